// Round 4
// baseline (446.655 us; speedup 1.0000x reference)
//
#include <hip/hip_runtime.h>

// FeatureCorrelation: B=8192 rows x 3 steps x D=2048 fp32.
// Per row: reductions -> weights -> 3 linear-combo outputs.
// 201 MB in + 201 MB out; floor ~64 us @ 6.3 TB/s achievable.
//
// R7 == R6 resubmit (R6 bench was an infra failure -- container acquisition,
// no counters produced; do not fork the A/B).
//
// R6: two-pass "read twice, hold nothing".
//  - R4 (121 us, 2.4 TB/s): wave-per-row single pass. Row data needed twice
//    (reduce, then combine) -> 96 VGPRs/row live across the whole row lifetime
//    -> bulk-synchronous convoy, memory pipe duty-cycles, VALUBusy 9%.
//  - R5 (144 us): 2-deep row pipeline. VGPR=128 + FETCH/WRITE both +47 MB =
//    the second row buffer SPILLED to scratch. Registers can't hold 2 rows.
//  - Now: K1 streams feat once, produces 6 combine coefficients per row
//    (32 B/row -> 256 KB workspace). K2 re-streams feat (L3-resident: input
//    is 201 MB < 256 MB L3; R4 showed ~50% L3 service on first read) and does
//    load->combine->NT-store with ~no live state. Both kernels are rolling
//    streams with __launch_bounds__(256,6) (VGPR cap ~85 at 6 waves/SIMD,
//    per m69's pool=512/SIMD) so the compiler cannot hoard a load burst.
//  - eps-sum term dropped: 2*EPS_PD*(Si-Sj) ~ 2e-4 inside a sqrt arg of ~8e3
//    -> ~1e-9 relative in w -> invisible at absmax tolerance. Keeps D*eps^2.

constexpr int D   = 2048;
constexpr int TPB = 256;                 // 4 waves per block
constexpr int WPB = TPB / 64;            // rows (waves) per block
constexpr int NC  = D / (64 * 4);        // fvec4 chunks per lane per vector = 8
constexpr float EPS_PD = 1e-6f;
constexpr float EPS_CS = 1e-8f;

using fvec4 = __attribute__((ext_vector_type(4))) float;

// ---------------- K1: per-row reduce -> 6 combine coefficients ----------------
__global__ __launch_bounds__(TPB, 6) void feat_corr_reduce(
    const float* __restrict__ feat,
    const float* __restrict__ pos,
    float* __restrict__ coef,            // 8 floats per row (6 used + pad)
    int B)
{
    // pos (24 KB) in LDS: pos reads leave the vmcnt queue entirely.
    __shared__ float psh[3 * D];
    {
        const fvec4* ps = (const fvec4*)pos;
        fvec4*       pd = (fvec4*)psh;
        for (int i = threadIdx.x; i < 3 * D / 4; i += TPB) pd[i] = ps[i];
    }
    __syncthreads();

    const int lane = threadIdx.x & 63;
    const int b    = blockIdx.x * WPB + (threadIdx.x >> 6);
    if (b >= B) return;

    const fvec4* r1 = (const fvec4*)(feat + (size_t)b * (3 * D));
    const fvec4* r2 = r1 + D / 4;
    const fvec4* r3 = r2 + D / 4;
    const fvec4* p1 = (const fvec4*)psh;
    const fvec4* p2 = p1 + D / 4;
    const fvec4* p3 = p2 + D / 4;

    // Rolling stream: load chunk -> 24 FMA -> next. 6 accumulators only.
    float n1s = 0.f, n2s = 0.f, n3s = 0.f;
    float d12 = 0.f, d13 = 0.f, d23 = 0.f;
#pragma unroll
    for (int j = 0; j < NC; ++j) {
        const int idx = j * 64 + lane;
        const fvec4 u4 = r1[idx] + p1[idx];
        const fvec4 w4 = r2[idx] + p2[idx];
        const fvec4 z4 = r3[idx] + p3[idx];
#pragma unroll
        for (int k = 0; k < 4; ++k) {
            const float u = u4[k], w = w4[k], z = z4[k];
            n1s = fmaf(u, u, n1s);
            n2s = fmaf(w, w, n2s);
            n3s = fmaf(z, z, n3s);
            d12 = fmaf(u, w, d12);
            d13 = fmaf(u, z, d13);
            d23 = fmaf(w, z, d23);
        }
    }

    // 64-lane butterfly on 6 values.
    float vals[6] = {n1s, n2s, n3s, d12, d13, d23};
#pragma unroll
    for (int off = 1; off < 64; off <<= 1) {
#pragma unroll
        for (int k = 0; k < 6; ++k)
            vals[k] += __shfl_xor(vals[k], off, 64);
    }

    const float N1s = vals[0], N2s = vals[1], N3s = vals[2];
    const float D12 = vals[3], D13 = vals[4], D23 = vals[5];

    const float n1 = fmaxf(sqrtf(N1s), EPS_CS);
    const float n2 = fmaxf(sqrtf(N2s), EPS_CS);
    const float n3 = fmaxf(sqrtf(N3s), EPS_CS);

    const float c12 = 0.5f + 0.5f * (D12 / (n1 * n2));   // cosine terms (symmetric)
    const float c13 = 0.5f + 0.5f * (D13 / (n1 * n3));
    const float c23 = 0.5f + 0.5f * (D23 / (n2 * n3));

    const float sq12 = N1s + N2s - 2.f * D12;            // sum((fi-fj)^2)
    const float sq13 = N1s + N3s - 2.f * D13;
    const float sq23 = N2s + N3s - 2.f * D23;
    const float De2  = (float)D * EPS_PD * EPS_PD;

    // 1/(1+sqrt(sum((fi-fj+eps)^2))); the 2*eps*(Si-Sj) cross-term is ~1e-9
    // relative -> dropped (see header). Symmetric now: wij == wji.
    const float w12 = 1.0f / (1.0f + sqrtf(sq12 + De2));
    const float w13 = 1.0f / (1.0f + sqrtf(sq13 + De2));
    const float w23 = 1.0f / (1.0f + sqrtf(sq23 + De2));

    // o1 = f1 + (w12+c12) f2 + (w13+c13) f3   (cyclic)
    if (lane == 0) {
        fvec4* cv = (fvec4*)(coef + (size_t)b * 8);
        fvec4 c0 = {w12 + c12, w13 + c13, w12 + c12, w23 + c23}; // g1b g1c g2a g2c
        fvec4 c1 = {w13 + c13, w23 + c23, 0.f, 0.f};             // g3a g3b
        cv[0] = c0;
        cv[1] = c1;
    }
}

// ---------------- K2: per-row combine (streaming, ~no live state) ----------------
__global__ __launch_bounds__(TPB, 6) void feat_corr_combine(
    const float* __restrict__ feat,
    const float* __restrict__ pos,
    const float* __restrict__ coef,
    float* __restrict__ out,
    int B)
{
    __shared__ float psh[3 * D];
    {
        const fvec4* ps = (const fvec4*)pos;
        fvec4*       pd = (fvec4*)psh;
        for (int i = threadIdx.x; i < 3 * D / 4; i += TPB) pd[i] = ps[i];
    }
    __syncthreads();

    const int lane = threadIdx.x & 63;
    const int b    = blockIdx.x * WPB + (threadIdx.x >> 6);
    if (b >= B) return;

    // Broadcast coeff load (same addr all lanes -> 1 transaction, L2-hot).
    const fvec4* cv = (const fvec4*)(coef + (size_t)b * 8);
    const fvec4 c0 = cv[0], c1 = cv[1];
    const float g1b = c0[0], g1c = c0[1], g2a = c0[2], g2c = c0[3];
    const float g3a = c1[0], g3b = c1[1];

    const size_t row = (size_t)b * (3 * D);
    const fvec4* r1 = (const fvec4*)(feat + row);
    const fvec4* r2 = r1 + D / 4;
    const fvec4* r3 = r2 + D / 4;
    const fvec4* p1 = (const fvec4*)psh;
    const fvec4* p2 = p1 + D / 4;
    const fvec4* p3 = p2 + D / 4;
    fvec4* o1 = (fvec4*)(out + row);
    fvec4* o2 = o1 + D / 4;
    fvec4* o3 = o2 + D / 4;

    // Rolling stream: 3 loads (L3-hot re-read) -> 3 combos -> 3 NT stores.
#pragma unroll
    for (int j = 0; j < NC; ++j) {
        const int idx = j * 64 + lane;
        const fvec4 x1 = r1[idx] + p1[idx];
        const fvec4 x2 = r2[idx] + p2[idx];
        const fvec4 x3 = r3[idx] + p3[idx];
        const fvec4 q1 = x1 + g1b * x2 + g1c * x3;
        const fvec4 q2 = x2 + g2a * x1 + g2c * x3;
        const fvec4 q3 = x3 + g3a * x1 + g3b * x2;
        __builtin_nontemporal_store(q1, o1 + idx);   // streamed out, never re-read
        __builtin_nontemporal_store(q2, o2 + idx);
        __builtin_nontemporal_store(q3, o3 + idx);
    }
}

// ---------------- Fallback: single-pass (if workspace too small) ----------------
__global__ __launch_bounds__(TPB) void feat_corr_single(
    const float* __restrict__ feat,
    const float* __restrict__ pos,
    float* __restrict__ out,
    int B)
{
    const int lane = threadIdx.x & 63;
    const int b    = blockIdx.x * WPB + (threadIdx.x >> 6);
    if (b >= B) return;

    const size_t row = (size_t)b * (3 * D);
    const fvec4* r1 = (const fvec4*)(feat + row);
    const fvec4* r2 = r1 + D / 4;
    const fvec4* r3 = r2 + D / 4;
    const fvec4* p1 = (const fvec4*)pos;
    const fvec4* p2 = p1 + D / 4;
    const fvec4* p3 = p2 + D / 4;

    fvec4 x1[NC], x2[NC], x3[NC];
#pragma unroll
    for (int j = 0; j < NC; ++j) x1[j] = r1[j * 64 + lane];
#pragma unroll
    for (int j = 0; j < NC; ++j) x2[j] = r2[j * 64 + lane];
#pragma unroll
    for (int j = 0; j < NC; ++j) x3[j] = r3[j * 64 + lane];
#pragma unroll
    for (int j = 0; j < NC; ++j) {
        x1[j] += p1[j * 64 + lane];
        x2[j] += p2[j * 64 + lane];
        x3[j] += p3[j * 64 + lane];
    }

    float n1s = 0.f, n2s = 0.f, n3s = 0.f, d12 = 0.f, d13 = 0.f, d23 = 0.f;
#pragma unroll
    for (int j = 0; j < NC; ++j)
#pragma unroll
        for (int k = 0; k < 4; ++k) {
            const float u = x1[j][k], w = x2[j][k], z = x3[j][k];
            n1s = fmaf(u, u, n1s); n2s = fmaf(w, w, n2s); n3s = fmaf(z, z, n3s);
            d12 = fmaf(u, w, d12); d13 = fmaf(u, z, d13); d23 = fmaf(w, z, d23);
        }

    float vals[6] = {n1s, n2s, n3s, d12, d13, d23};
#pragma unroll
    for (int off = 1; off < 64; off <<= 1)
#pragma unroll
        for (int k = 0; k < 6; ++k) vals[k] += __shfl_xor(vals[k], off, 64);

    const float N1s = vals[0], N2s = vals[1], N3s = vals[2];
    const float D12 = vals[3], D13 = vals[4], D23 = vals[5];
    const float n1 = fmaxf(sqrtf(N1s), EPS_CS);
    const float n2 = fmaxf(sqrtf(N2s), EPS_CS);
    const float n3 = fmaxf(sqrtf(N3s), EPS_CS);
    const float c12 = 0.5f + 0.5f * (D12 / (n1 * n2));
    const float c13 = 0.5f + 0.5f * (D13 / (n1 * n3));
    const float c23 = 0.5f + 0.5f * (D23 / (n2 * n3));
    const float De2 = (float)D * EPS_PD * EPS_PD;
    const float w12 = 1.0f / (1.0f + sqrtf(N1s + N2s - 2.f * D12 + De2));
    const float w13 = 1.0f / (1.0f + sqrtf(N1s + N3s - 2.f * D13 + De2));
    const float w23 = 1.0f / (1.0f + sqrtf(N2s + N3s - 2.f * D23 + De2));
    const float g1b = w12 + c12, g1c = w13 + c13;
    const float g2a = w12 + c12, g2c = w23 + c23;
    const float g3a = w13 + c13, g3b = w23 + c23;

    fvec4* o1 = (fvec4*)(out + row);
    fvec4* o2 = o1 + D / 4;
    fvec4* o3 = o2 + D / 4;
#pragma unroll
    for (int j = 0; j < NC; ++j) {
        const int idx = j * 64 + lane;
        __builtin_nontemporal_store(x1[j] + g1b * x2[j] + g1c * x3[j], o1 + idx);
        __builtin_nontemporal_store(x2[j] + g2a * x1[j] + g2c * x3[j], o2 + idx);
        __builtin_nontemporal_store(x3[j] + g3a * x1[j] + g3b * x2[j], o3 + idx);
    }
}

extern "C" void kernel_launch(void* const* d_in, const int* in_sizes, int n_in,
                              void* d_out, int out_size, void* d_ws, size_t ws_size,
                              hipStream_t stream) {
    const float* feat = (const float*)d_in[0];
    const float* pos  = (const float*)d_in[1];
    float* out        = (float*)d_out;
    const int B = in_sizes[0] / (3 * D);        // element-count semantics (verified R4)
    const int grid = (B + WPB - 1) / WPB;
    const size_t need = (size_t)B * 8 * sizeof(float);   // 256 KB coeff workspace

    if (d_ws != nullptr && ws_size >= need) {
        float* coef = (float*)d_ws;
        feat_corr_reduce<<<grid, TPB, 0, stream>>>(feat, pos, coef, B);
        feat_corr_combine<<<grid, TPB, 0, stream>>>(feat, pos, coef, out, B);
    } else {
        feat_corr_single<<<grid, TPB, 0, stream>>>(feat, pos, out, B);
    }
}

// Round 5
// 348.590 us; speedup vs baseline: 1.2813x; 1.2813x over previous
//
#include <hip/hip_runtime.h>

// FeatureCorrelation: B=8192 rows x 3 steps x D=2048 fp32.
// 201 MB in + 201 MB out; floor ~64 us @ 6.3 TB/s achievable.
//
// R8: fused reduce+combine, cache-mediated second read.
// Evidence trail:
//  - R0 (320us): block/row, max occupancy, bulk-sync -> 1.26 TB/s.
//  - R4 (121us): wave/row burst, 16 waves/CU -> 2.4 TB/s.
//  - R5 (144us): 2-row reg ping-pong -> VGPR 128 + spill (FETCH/WRITE +47MB).
//  - R6 two-pass: reduce-only kernel 143us @ 1.5 TB/s (VGPR 40, tiny window,
//    serial tail); combine kernel ~82us @ ~4.9 TB/s (rolling loads+stores).
//  => Occupancy is not the lever; per-wave memory-issue CONTINUITY is.
//     K2's shape (every chunk: loads + stores, no drain phases) is the fast one.
// This kernel: wave-per-row, 4 rows/wave. Steady state per chunk j:
//   load row_k chunk (HBM) | reload row_{k-1} chunk (L3-hot, touched ~20us ago,
//   churn ~100-150MB < 256MB L3) | reduce-FMA row_k | combine+NT-store row_{k-1}.
// Only the per-row butterfly+weights tail (~500cy) breaks the stream, amortized
// over 48 KB of traffic. No 2nd register buffer (R5 spill), no 2nd launch (R6).
// launch_bounds(256,4): VGPR cap 128 so the load window isn't strangled (K1's
// cap-85 gave VGPR=40 and a ~1-chunk window).

constexpr int D   = 2048;
constexpr int TPB = 256;                 // 4 waves per block
constexpr int WPB = TPB / 64;
constexpr int NC  = D / (64 * 4);        // 8 fvec4 chunks per vector per lane
constexpr float EPS_PD = 1e-6f;
constexpr float EPS_CS = 1e-8f;

using fvec4 = __attribute__((ext_vector_type(4))) float;

__global__ __launch_bounds__(TPB, 4) void feat_corr_fused(
    const float* __restrict__ feat,
    const float* __restrict__ pos,
    float* __restrict__ out,
    int B, int NW)                       // NW = total waves in grid
{
    // pos (24 KB) in LDS once per block: pos reads use the lgkm queue and
    // never perturb the global-load window.
    __shared__ float psh[3 * D];
    {
        const fvec4* ps = (const fvec4*)pos;
        fvec4*       pd = (fvec4*)psh;
#pragma unroll
        for (int i = threadIdx.x; i < 3 * D / 4; i += TPB) pd[i] = ps[i];
    }
    __syncthreads();                     // only barrier; no barriers after

    const int lane = threadIdx.x & 63;
    const int gw   = blockIdx.x * WPB + (threadIdx.x >> 6);
    if (gw >= B) return;

    const fvec4* p1 = (const fvec4*)psh;
    const fvec4* p2 = p1 + D / 4;
    const fvec4* p3 = p2 + D / 4;

    // Butterfly + weights -> 6 combine coefficients.
    // eps cross-term 2*EPS_PD*(Si-Sj) dropped (~1e-9 relative; R6 verified
    // passing). Weights become symmetric: wij == wji.
    auto finalize = [&](float v[6], float cf[6]) {
#pragma unroll
        for (int off = 1; off < 64; off <<= 1)
#pragma unroll
            for (int k = 0; k < 6; ++k) v[k] += __shfl_xor(v[k], off, 64);
        const float N1s = v[0], N2s = v[1], N3s = v[2];
        const float D12 = v[3], D13 = v[4], D23 = v[5];
        const float n1 = fmaxf(sqrtf(N1s), EPS_CS);
        const float n2 = fmaxf(sqrtf(N2s), EPS_CS);
        const float n3 = fmaxf(sqrtf(N3s), EPS_CS);
        const float c12 = 0.5f + 0.5f * (D12 / (n1 * n2));
        const float c13 = 0.5f + 0.5f * (D13 / (n1 * n3));
        const float c23 = 0.5f + 0.5f * (D23 / (n2 * n3));
        const float De2 = (float)D * EPS_PD * EPS_PD;
        const float w12 = 1.f / (1.f + sqrtf(N1s + N2s - 2.f * D12 + De2));
        const float w13 = 1.f / (1.f + sqrtf(N1s + N3s - 2.f * D13 + De2));
        const float w23 = 1.f / (1.f + sqrtf(N2s + N3s - 2.f * D23 + De2));
        cf[0] = w12 + c12;  // g1b   o1 = x1 + g1b*x2 + g1c*x3
        cf[1] = w13 + c13;  // g1c
        cf[2] = w12 + c12;  // g2a   o2 = x2 + g2a*x1 + g2c*x3
        cf[3] = w23 + c23;  // g2c
        cf[4] = w13 + c13;  // g3a   o3 = x3 + g3a*x1 + g3b*x2
        cf[5] = w23 + c23;  // g3b
    };

    // ---- Prologue: pure reduce of this wave's first row.
    int rp = gw;                          // row with combine pending
    float cf[6];
    {
        const fvec4* a1 = (const fvec4*)(feat + (size_t)rp * (3 * D));
        const fvec4* a2 = a1 + D / 4;
        const fvec4* a3 = a2 + D / 4;
        float acc[6] = {0.f, 0.f, 0.f, 0.f, 0.f, 0.f};
#pragma unroll 2
        for (int j = 0; j < NC; ++j) {
            const int idx = j * 64 + lane;
            const fvec4 u = a1[idx] + p1[idx];
            const fvec4 w = a2[idx] + p2[idx];
            const fvec4 z = a3[idx] + p3[idx];
#pragma unroll
            for (int k = 0; k < 4; ++k) {
                acc[0] = fmaf(u[k], u[k], acc[0]);
                acc[1] = fmaf(w[k], w[k], acc[1]);
                acc[2] = fmaf(z[k], z[k], acc[2]);
                acc[3] = fmaf(u[k], w[k], acc[3]);
                acc[4] = fmaf(u[k], z[k], acc[4]);
                acc[5] = fmaf(w[k], z[k], acc[5]);
            }
        }
        finalize(acc, cf);
    }

    // ---- Steady state: reduce row r  ||  combine+store row rp (cache-hot).
    for (int r = rp + NW; r < B; r += NW) {
        const fvec4* a1 = (const fvec4*)(feat + (size_t)r  * (3 * D));
        const fvec4* a2 = a1 + D / 4;
        const fvec4* a3 = a2 + D / 4;
        const fvec4* b1 = (const fvec4*)(feat + (size_t)rp * (3 * D));
        const fvec4* b2 = b1 + D / 4;
        const fvec4* b3 = b2 + D / 4;
        fvec4* o1 = (fvec4*)(out + (size_t)rp * (3 * D));
        fvec4* o2 = o1 + D / 4;
        fvec4* o3 = o2 + D / 4;
        const float g1b = cf[0], g1c = cf[1], g2a = cf[2];
        const float g2c = cf[3], g3a = cf[4], g3b = cf[5];

        float acc[6] = {0.f, 0.f, 0.f, 0.f, 0.f, 0.f};
#pragma unroll 2
        for (int j = 0; j < NC; ++j) {
            const int idx = j * 64 + lane;
            const fvec4 q1 = p1[idx], q2 = p2[idx], q3 = p3[idx];
            const fvec4 u  = a1[idx] + q1;        // new row: HBM stream
            const fvec4 w  = a2[idx] + q2;
            const fvec4 z  = a3[idx] + q3;
            const fvec4 x1 = b1[idx] + q1;        // pending row: L3-hot re-read
            const fvec4 x2 = b2[idx] + q2;
            const fvec4 x3 = b3[idx] + q3;
#pragma unroll
            for (int k = 0; k < 4; ++k) {
                acc[0] = fmaf(u[k], u[k], acc[0]);
                acc[1] = fmaf(w[k], w[k], acc[1]);
                acc[2] = fmaf(z[k], z[k], acc[2]);
                acc[3] = fmaf(u[k], w[k], acc[3]);
                acc[4] = fmaf(u[k], z[k], acc[4]);
                acc[5] = fmaf(w[k], z[k], acc[5]);
            }
            __builtin_nontemporal_store(x1 + g1b * x2 + g1c * x3, o1 + idx);
            __builtin_nontemporal_store(x2 + g2a * x1 + g2c * x3, o2 + idx);
            __builtin_nontemporal_store(x3 + g3a * x1 + g3b * x2, o3 + idx);
        }
        finalize(acc, cf);
        rp = r;
    }

    // ---- Epilogue: combine the last pending row.
    {
        const fvec4* b1 = (const fvec4*)(feat + (size_t)rp * (3 * D));
        const fvec4* b2 = b1 + D / 4;
        const fvec4* b3 = b2 + D / 4;
        fvec4* o1 = (fvec4*)(out + (size_t)rp * (3 * D));
        fvec4* o2 = o1 + D / 4;
        fvec4* o3 = o2 + D / 4;
        const float g1b = cf[0], g1c = cf[1], g2a = cf[2];
        const float g2c = cf[3], g3a = cf[4], g3b = cf[5];
#pragma unroll 2
        for (int j = 0; j < NC; ++j) {
            const int idx = j * 64 + lane;
            const fvec4 q1 = p1[idx], q2 = p2[idx], q3 = p3[idx];
            const fvec4 x1 = b1[idx] + q1;
            const fvec4 x2 = b2[idx] + q2;
            const fvec4 x3 = b3[idx] + q3;
            __builtin_nontemporal_store(x1 + g1b * x2 + g1c * x3, o1 + idx);
            __builtin_nontemporal_store(x2 + g2a * x1 + g2c * x3, o2 + idx);
            __builtin_nontemporal_store(x3 + g3a * x1 + g3b * x2, o3 + idx);
        }
    }
}

extern "C" void kernel_launch(void* const* d_in, const int* in_sizes, int n_in,
                              void* d_out, int out_size, void* d_ws, size_t ws_size,
                              hipStream_t stream) {
    const float* feat = (const float*)d_in[0];
    const float* pos  = (const float*)d_in[1];
    float* out        = (float*)d_out;
    const int B = in_sizes[0] / (3 * D);     // rows (element-count semantics, verified)

    // 512 blocks x 4 waves = 2048 waves -> 4 rows/wave at B=8192:
    // 3 of 4 row-passes run fully interleaved (reduce || combine+store).
    int blocks = 512;
    if (blocks * WPB > B) blocks = (B + WPB - 1) / WPB;
    const int NW = blocks * WPB;
    feat_corr_fused<<<blocks, TPB, 0, stream>>>(feat, pos, out, B, NW);
}